// Round 1
// baseline (376.998 us; speedup 1.0000x reference)
//
#include <hip/hip_runtime.h>

// EmbeddedLogRegClassifier: fused gather-pool + logreg head.
// pooled[b, d]        = (1/L) * sum_{v,l} emb[diag_idx[b,v,l], d]
// pooled[b, D+d]      = (1/L) * sum_{v,l} emb[proc_idx[b,v,l], d]
// out[b, c]           = bias[c] + sum_k pooled[b, k] * W[c, k]

constexpr int B      = 2048;
constexpr int V      = 50;
constexpr int L      = 20;
constexpr int D      = 128;
constexpr int NIDX   = V * L;    // 1000 indices per (sample, half)
constexpr int NCLASS = 128;
constexpr int TWO_D  = 2 * D;    // 256

__global__ __launch_bounds__(256, 4)
void pool_gemm_kernel(const int* __restrict__ diag_idx,
                      const int* __restrict__ proc_idx,
                      const float* __restrict__ emb,
                      const float* __restrict__ W,
                      const float* __restrict__ bias,
                      float* __restrict__ out)
{
    // wave 0,1 -> diag (index chunks 0/1); wave 2,3 -> proc (chunks 0/1)
    __shared__ float partial[4][D];   // per-wave partial sums
    __shared__ float x_lds[TWO_D];    // pooled concat vector for this sample

    const int b    = blockIdx.x;
    const int tid  = threadIdx.x;
    const int wave = tid >> 6;
    const int lane = tid & 63;

    const int half  = wave >> 1;      // 0 = diag, 1 = proc
    const int chunk = wave & 1;       // which 500-index sub-range
    const int* __restrict__ idx =
        (half == 0 ? diag_idx : proc_idx) + (size_t)b * NIDX + (size_t)chunk * (NIDX / 2);

    const float2* __restrict__ embv = reinterpret_cast<const float2*>(emb);

    // Each lane accumulates dims [2*lane, 2*lane+1]; one wave iteration reads
    // one full 512B embedding row (64 lanes x float2), perfectly coalesced.
    float ax = 0.f, ay = 0.f;
    #pragma unroll 4
    for (int i = 0; i < NIDX / 2; ++i) {
        const int   r = idx[i];                              // wave-uniform -> s_load
        const float2 e = embv[(size_t)r * (D / 2) + lane];
        ax += e.x;
        ay += e.y;
    }
    partial[wave][lane * 2]     = ax;
    partial[wave][lane * 2 + 1] = ay;
    __syncthreads();

    // Combine the two index-chunk waves per half, apply 1/L (mean over L, sum over V).
    {
        const int h = tid >> 7;        // 0 = diag half, 1 = proc half
        const int d = tid & (D - 1);
        x_lds[tid] = (partial[2 * h][d] + partial[2 * h + 1][d]) * (1.0f / L);
    }
    __syncthreads();

    // Logreg head: thread c computes out[b, c]. W row read as float4 (L2-resident,
    // reused by all 2048 blocks); x_lds reads are wave-uniform broadcasts.
    if (tid < NCLASS) {
        const float4* __restrict__ wrow =
            reinterpret_cast<const float4*>(W + (size_t)tid * TWO_D);
        const float4* __restrict__ xv = reinterpret_cast<const float4*>(x_lds);
        float s = bias[tid];
        #pragma unroll 8
        for (int k = 0; k < TWO_D / 4; ++k) {
            const float4 w4 = wrow[k];
            const float4 x4 = xv[k];
            s = fmaf(w4.x, x4.x, s);
            s = fmaf(w4.y, x4.y, s);
            s = fmaf(w4.z, x4.z, s);
            s = fmaf(w4.w, x4.w, s);
        }
        out[(size_t)b * NCLASS + tid] = s;
    }
}

extern "C" void kernel_launch(void* const* d_in, const int* in_sizes, int n_in,
                              void* d_out, int out_size, void* d_ws, size_t ws_size,
                              hipStream_t stream)
{
    const int*   diag = (const int*)d_in[0];
    const int*   proc = (const int*)d_in[1];
    const float* emb  = (const float*)d_in[2];
    const float* W    = (const float*)d_in[3];
    const float* bias = (const float*)d_in[4];
    float*       out  = (float*)d_out;

    pool_gemm_kernel<<<B, 256, 0, stream>>>(diag, proc, emb, W, bias, out);
}

// Round 2
// 354.803 us; speedup vs baseline: 1.0626x; 1.0626x over previous
//
#include <hip/hip_runtime.h>

// EmbeddedLogRegClassifier: fused gather-pool + logreg head.
// pooled[b, d]   = (1/L) * sum_{v,l} emb[diag_idx[b,v,l], d]
// pooled[b, D+d] = (1/L) * sum_{v,l} emb[proc_idx[b,v,l], d]
// out[b, c]      = bias[c] + sum_k pooled[b, k] * W[c, k]

constexpr int B      = 2048;
constexpr int V      = 50;
constexpr int L      = 20;
constexpr int D      = 128;
constexpr int NIDX   = V * L;    // 1000 indices per (sample, half)
constexpr int NCLASS = 128;
constexpr int TWO_D  = 2 * D;    // 256

__global__ __launch_bounds__(256, 4)
void pool_gemm_kernel(const int* __restrict__ diag_idx,
                      const int* __restrict__ proc_idx,
                      const float* __restrict__ emb,
                      const float* __restrict__ W,
                      const float* __restrict__ bias,
                      float* __restrict__ out)
{
    // wave 0,1 -> diag (index chunks 0/1); wave 2,3 -> proc (chunks 0/1)
    __shared__ float4 part4[4][64];   // per-wave partial sums (float4 per lane)
    __shared__ float  x_lds[TWO_D];   // pooled concat vector for this sample

    const int b    = blockIdx.x;
    const int tid  = threadIdx.x;
    const int wave = tid >> 6;
    const int lane = tid & 63;

    const int half  = wave >> 1;      // 0 = diag, 1 = proc
    const int chunk = wave & 1;       // which 500-index sub-range
    const int* __restrict__ idx =
        (half == 0 ? diag_idx : proc_idx) + (size_t)b * NIDX + (size_t)chunk * (NIDX / 2);
    // 500 indices per wave, consumed 2 rows per iteration.
    const int2* __restrict__ idx2 = reinterpret_cast<const int2*>(idx);

    const float4* __restrict__ emb4 = reinterpret_cast<const float4*>(emb);
    const int c = lane & 31;          // dim group: this lane covers dims [4c, 4c+3]

    // Lanes 0-31 take even rows (p.x), lanes 32-63 take odd rows (p.y).
    // One load instruction fetches 1 KB = 2 full embedding rows, coalesced.
    // unroll 5 -> 10 rows (5 KB) in flight per wave for memory-level parallelism.
    float4 acc = make_float4(0.f, 0.f, 0.f, 0.f);
    #pragma unroll 5
    for (int i = 0; i < NIDX / 4; ++i) {          // 250 iterations
        const int2 p = idx2[i];                   // wave-uniform -> s_load_dwordx2
        const int  r = (lane & 32) ? p.y : p.x;
        const float4 e = emb4[(size_t)r * (D / 4) + c];
        acc.x += e.x; acc.y += e.y; acc.z += e.z; acc.w += e.w;
    }
    part4[wave][lane] = acc;
    __syncthreads();

    // Combine: pooled[h*D + 4c + j] over waves {2h, 2h+1} and lanes {c, c+32},
    // scaled by 1/L (mean over codes, sum over visits).
    {
        const int h   = tid >> 7;          // 0 = diag half, 1 = proc half
        const int rem = tid & 127;
        const int cc  = rem >> 2;
        const int j   = rem & 3;
        const float* p0 = reinterpret_cast<const float*>(&part4[2 * h][cc]);
        const float* p1 = reinterpret_cast<const float*>(&part4[2 * h][cc + 32]);
        const float* p2 = reinterpret_cast<const float*>(&part4[2 * h + 1][cc]);
        const float* p3 = reinterpret_cast<const float*>(&part4[2 * h + 1][cc + 32]);
        x_lds[tid] = (p0[j] + p1[j] + p2[j] + p3[j]) * (1.0f / L);
    }
    __syncthreads();

    // Logreg head: thread c computes out[b, c]. W rows are L2-resident (128 KB,
    // reused by all 2048 blocks); x_lds reads are wave-uniform broadcasts.
    if (tid < NCLASS) {
        const float4* __restrict__ wrow =
            reinterpret_cast<const float4*>(W + (size_t)tid * TWO_D);
        const float4* __restrict__ xv = reinterpret_cast<const float4*>(x_lds);
        float s = bias[tid];
        #pragma unroll 8
        for (int k = 0; k < TWO_D / 4; ++k) {
            const float4 w4 = wrow[k];
            const float4 x4 = xv[k];
            s = fmaf(w4.x, x4.x, s);
            s = fmaf(w4.y, x4.y, s);
            s = fmaf(w4.z, x4.z, s);
            s = fmaf(w4.w, x4.w, s);
        }
        out[(size_t)b * NCLASS + tid] = s;
    }
}

extern "C" void kernel_launch(void* const* d_in, const int* in_sizes, int n_in,
                              void* d_out, int out_size, void* d_ws, size_t ws_size,
                              hipStream_t stream)
{
    const int*   diag = (const int*)d_in[0];
    const int*   proc = (const int*)d_in[1];
    const float* emb  = (const float*)d_in[2];
    const float* W    = (const float*)d_in[3];
    const float* bias = (const float*)d_in[4];
    float*       out  = (float*)d_out;

    pool_gemm_kernel<<<B, 256, 0, stream>>>(diag, proc, emb, W, bias, out);
}

// Round 3
// 241.243 us; speedup vs baseline: 1.5627x; 1.4707x over previous
//
#include <hip/hip_runtime.h>

// EmbeddedLogRegClassifier: fused gather-pool + logreg head.
// pooled[b, d]   = (1/L) * sum_{v,l} emb[diag_idx[b,v,l], d]
// pooled[b, D+d] = (1/L) * sum_{v,l} emb[proc_idx[b,v,l], d]
// out[b, c]      = bias[c] + sum_k pooled[b, k] * W[c, k]
//
// R3: gather path is L3/fabric-BW-bound (~3.5 TB/s on L2-miss traffic).
// Convert emb to bf16 in d_ws each launch: halves gather bytes AND halves
// the gathered footprint (51.2 -> 25.6 MB) for better L2 residency.

constexpr int B      = 2048;
constexpr int V      = 50;
constexpr int L      = 20;
constexpr int D      = 128;
constexpr int NIDX   = V * L;    // 1000 indices per (sample, half)
constexpr int NCLASS = 128;
constexpr int TWO_D  = 2 * D;    // 256
constexpr int VOCAB  = 100000;

__device__ __forceinline__ unsigned short f2bf_rne(float f) {
    unsigned int u = __float_as_uint(f);
    unsigned int r = (u + 0x7FFFu + ((u >> 16) & 1u)) >> 16;   // round-nearest-even
    return (unsigned short)r;
}

// ---- pre-pass: emb fp32 -> bf16 (row-major, same layout) -------------------
__global__ __launch_bounds__(256)
void convert_kernel(const float* __restrict__ emb, unsigned short* __restrict__ out)
{
    const int i = blockIdx.x * 256 + threadIdx.x;      // one float4 per thread
    const float4 v = reinterpret_cast<const float4*>(emb)[i];
    ushort4 o;
    o.x = f2bf_rne(v.x);
    o.y = f2bf_rne(v.y);
    o.z = f2bf_rne(v.z);
    o.w = f2bf_rne(v.w);
    reinterpret_cast<ushort4*>(out)[i] = o;
}

// ---- main: bf16 gather-pool + fp32 head ------------------------------------
__global__ __launch_bounds__(256, 4)
void pool_gemm_bf16_kernel(const int* __restrict__ diag_idx,
                           const int* __restrict__ proc_idx,
                           const unsigned short* __restrict__ embb,
                           const float* __restrict__ W,
                           const float* __restrict__ bias,
                           float* __restrict__ out)
{
    __shared__ float4 part4[4][64];   // per-wave partial sums (float4 per lane)
    __shared__ float  x_lds[TWO_D];

    const int b    = blockIdx.x;
    const int tid  = threadIdx.x;
    const int wave = tid >> 6;
    const int lane = tid & 63;

    const int half  = wave >> 1;      // 0 = diag, 1 = proc
    const int chunk = wave & 1;       // which 500-index sub-range
    const int* __restrict__ idx =
        (half == 0 ? diag_idx : proc_idx) + (size_t)b * NIDX + (size_t)chunk * (NIDX / 2);
    const int2* __restrict__ idx2 = reinterpret_cast<const int2*>(idx);

    // bf16 row = 256 B = 32 lanes x ushort4(8 B). Lanes 0-31 even row, 32-63 odd.
    const ushort4* __restrict__ emb4 = reinterpret_cast<const ushort4*>(embb);
    const int c = lane & 31;          // dims [4c, 4c+3]

    float4 acc = make_float4(0.f, 0.f, 0.f, 0.f);
    #pragma unroll 10
    for (int i = 0; i < NIDX / 4; ++i) {          // 250 iterations, 2 rows each
        const int2 p = idx2[i];                   // wave-uniform -> s_load_dwordx2
        const int  r = (lane & 32) ? p.y : p.x;
        const ushort4 e = emb4[(size_t)r * (D / 4) + c];
        acc.x += __uint_as_float((unsigned int)e.x << 16);
        acc.y += __uint_as_float((unsigned int)e.y << 16);
        acc.z += __uint_as_float((unsigned int)e.z << 16);
        acc.w += __uint_as_float((unsigned int)e.w << 16);
    }
    part4[wave][lane] = acc;
    __syncthreads();

    // pooled[h*D + 4c + j] = (waves {2h,2h+1}, lanes {c, c+32}) summed, * 1/L
    {
        const int h   = tid >> 7;
        const int rem = tid & 127;
        const int cc  = rem >> 2;
        const int j   = rem & 3;
        const float* p0 = reinterpret_cast<const float*>(&part4[2 * h][cc]);
        const float* p1 = reinterpret_cast<const float*>(&part4[2 * h][cc + 32]);
        const float* p2 = reinterpret_cast<const float*>(&part4[2 * h + 1][cc]);
        const float* p3 = reinterpret_cast<const float*>(&part4[2 * h + 1][cc + 32]);
        x_lds[tid] = (p0[j] + p1[j] + p2[j] + p3[j]) * (1.0f / L);
    }
    __syncthreads();

    if (tid < NCLASS) {
        const float4* __restrict__ wrow =
            reinterpret_cast<const float4*>(W + (size_t)tid * TWO_D);
        const float4* __restrict__ xv = reinterpret_cast<const float4*>(x_lds);
        float s = bias[tid];
        #pragma unroll 8
        for (int k = 0; k < TWO_D / 4; ++k) {
            const float4 w4 = wrow[k];
            const float4 x4 = xv[k];
            s = fmaf(w4.x, x4.x, s);
            s = fmaf(w4.y, x4.y, s);
            s = fmaf(w4.z, x4.z, s);
            s = fmaf(w4.w, x4.w, s);
        }
        out[(size_t)b * NCLASS + tid] = s;
    }
}

// ---- fallback fp32 gather (used only if d_ws can't hold bf16 emb) ----------
__global__ __launch_bounds__(256, 4)
void pool_gemm_f32_kernel(const int* __restrict__ diag_idx,
                          const int* __restrict__ proc_idx,
                          const float* __restrict__ emb,
                          const float* __restrict__ W,
                          const float* __restrict__ bias,
                          float* __restrict__ out)
{
    __shared__ float4 part4[4][64];
    __shared__ float  x_lds[TWO_D];

    const int b    = blockIdx.x;
    const int tid  = threadIdx.x;
    const int wave = tid >> 6;
    const int lane = tid & 63;

    const int half  = wave >> 1;
    const int chunk = wave & 1;
    const int* __restrict__ idx =
        (half == 0 ? diag_idx : proc_idx) + (size_t)b * NIDX + (size_t)chunk * (NIDX / 2);
    const int2* __restrict__ idx2 = reinterpret_cast<const int2*>(idx);

    const float4* __restrict__ emb4 = reinterpret_cast<const float4*>(emb);
    const int c = lane & 31;

    float4 acc = make_float4(0.f, 0.f, 0.f, 0.f);
    #pragma unroll 5
    for (int i = 0; i < NIDX / 4; ++i) {
        const int2 p = idx2[i];
        const int  r = (lane & 32) ? p.y : p.x;
        const float4 e = emb4[(size_t)r * (D / 4) + c];
        acc.x += e.x; acc.y += e.y; acc.z += e.z; acc.w += e.w;
    }
    part4[wave][lane] = acc;
    __syncthreads();

    {
        const int h   = tid >> 7;
        const int rem = tid & 127;
        const int cc  = rem >> 2;
        const int j   = rem & 3;
        const float* p0 = reinterpret_cast<const float*>(&part4[2 * h][cc]);
        const float* p1 = reinterpret_cast<const float*>(&part4[2 * h][cc + 32]);
        const float* p2 = reinterpret_cast<const float*>(&part4[2 * h + 1][cc]);
        const float* p3 = reinterpret_cast<const float*>(&part4[2 * h + 1][cc + 32]);
        x_lds[tid] = (p0[j] + p1[j] + p2[j] + p3[j]) * (1.0f / L);
    }
    __syncthreads();

    if (tid < NCLASS) {
        const float4* __restrict__ wrow =
            reinterpret_cast<const float4*>(W + (size_t)tid * TWO_D);
        const float4* __restrict__ xv = reinterpret_cast<const float4*>(x_lds);
        float s = bias[tid];
        #pragma unroll 8
        for (int k = 0; k < TWO_D / 4; ++k) {
            const float4 w4 = wrow[k];
            const float4 x4 = xv[k];
            s = fmaf(w4.x, x4.x, s);
            s = fmaf(w4.y, x4.y, s);
            s = fmaf(w4.z, x4.z, s);
            s = fmaf(w4.w, x4.w, s);
        }
        out[(size_t)b * NCLASS + tid] = s;
    }
}

extern "C" void kernel_launch(void* const* d_in, const int* in_sizes, int n_in,
                              void* d_out, int out_size, void* d_ws, size_t ws_size,
                              hipStream_t stream)
{
    const int*   diag = (const int*)d_in[0];
    const int*   proc = (const int*)d_in[1];
    const float* emb  = (const float*)d_in[2];
    const float* W    = (const float*)d_in[3];
    const float* bias = (const float*)d_in[4];
    float*       out  = (float*)d_out;

    const size_t emb_bf_bytes = (size_t)VOCAB * D * sizeof(unsigned short); // 25.6 MB

    if (ws_size >= emb_bf_bytes) {
        unsigned short* embb = (unsigned short*)d_ws;
        // 100000*128/4 float4s = 3,200,000 threads = 12500 blocks of 256
        convert_kernel<<<(VOCAB * D / 4) / 256, 256, 0, stream>>>(emb, embb);
        pool_gemm_bf16_kernel<<<B, 256, 0, stream>>>(diag, proc, embb, W, bias, out);
    } else {
        pool_gemm_f32_kernel<<<B, 256, 0, stream>>>(diag, proc, emb, W, bias, out);
    }
}

// Round 4
// 218.948 us; speedup vs baseline: 1.7219x; 1.1018x over previous
//
#include <hip/hip_runtime.h>

// EmbeddedLogRegClassifier: fused gather-pool + logreg head.
// pooled[b, d]   = (1/L) * sum_{v,l} emb[diag_idx[b,v,l], d]
// pooled[b, D+d] = (1/L) * sum_{v,l} emb[proc_idx[b,v,l], d]
// out[b, c]      = bias[c] + sum_k pooled[b, k] * W[c, k]
//
// R4: vocab-sliced gather. bf16 emb (R3) + split vocab into 8 slices of
// 3.2 MB; blocks with (blockIdx & 7) == s process only slice s. HW dispatch
// round-robins consecutive blockIdx across the 8 XCDs, so each XCD's 4 MB L2
// holds exactly its slice -> gather served at L2 BW (~34.5 TB/s aggregate)
// instead of the ~3 TB/s L3/fabric random path. Partial sums accumulate via
// global fp32 atomicAdd into pooled[B][256] (ws), then a small head kernel
// applies W/bias. Mapping is a perf heuristic only; correctness never
// depends on block->XCD placement.

constexpr int B      = 2048;
constexpr int V      = 50;
constexpr int L      = 20;
constexpr int D      = 128;
constexpr int NIDX   = V * L;     // 1000 indices per (sample, half)
constexpr int NCLASS = 128;
constexpr int TWO_D  = 2 * D;     // 256
constexpr int VOCAB  = 100000;
constexpr int NSLICE = 8;
constexpr int SLICE_ROWS = VOCAB / NSLICE;   // 12500

__device__ __forceinline__ unsigned short f2bf_rne(float f) {
    unsigned int u = __float_as_uint(f);
    unsigned int r = (u + 0x7FFFu + ((u >> 16) & 1u)) >> 16;   // round-nearest-even
    return (unsigned short)r;
}

// ---- pre-pass: emb fp32 -> bf16 (row-major, same layout) -------------------
__global__ __launch_bounds__(256)
void convert_kernel(const float* __restrict__ emb, unsigned short* __restrict__ out)
{
    const int i = blockIdx.x * 256 + threadIdx.x;      // one float4 per thread
    const float4 v = reinterpret_cast<const float4*>(emb)[i];
    ushort4 o;
    o.x = f2bf_rne(v.x);
    o.y = f2bf_rne(v.y);
    o.z = f2bf_rne(v.z);
    o.w = f2bf_rne(v.w);
    reinterpret_cast<ushort4*>(out)[i] = o;
}

// ---- wave-aggregated LDS compaction of in-slice indices --------------------
__device__ __forceinline__ void compact1(int r, int lo, int* __restrict__ list,
                                         int* __restrict__ cnt, int lane)
{
    const bool m = ((unsigned)(r - lo)) < (unsigned)SLICE_ROWS;
    const unsigned long long mask = __ballot(m);
    int base = 0;
    if (lane == 0 && mask) base = atomicAdd(cnt, (int)__popcll(mask));
    base = __builtin_amdgcn_readfirstlane(base);
    if (m) {
        const int pre = (int)__popcll(mask & ((1ull << lane) - 1ull));
        list[base + pre] = r - lo;
    }
}

// ---- sliced gather-pool ----------------------------------------------------
__global__ __launch_bounds__(256, 4)
void slice_pool_kernel(const int* __restrict__ diag_idx,
                       const int* __restrict__ proc_idx,
                       const unsigned short* __restrict__ embb,
                       float* __restrict__ pooled)
{
    __shared__ int   lists[2][NIDX];   // worst case: all 1000 idx in one slice
    __shared__ int   cnt[2];
    __shared__ float part[4][D];

    const int slice = blockIdx.x & (NSLICE - 1);   // == XCD under round-robin
    const int b     = blockIdx.x >> 3;
    const int tid   = threadIdx.x;
    const int lane  = tid & 63;
    const int wave  = tid >> 6;

    if (tid < 2) cnt[tid] = 0;
    __syncthreads();

    const int lo = slice * SLICE_ROWS;

    // Phase 1: ballot-compact in-slice indices (4 ints per thread, 250 int4s per half).
    {
        int4 q = make_int4(-1, -1, -1, -1);
        if (tid < NIDX / 4)
            q = reinterpret_cast<const int4*>(diag_idx + (size_t)b * NIDX)[tid];
        compact1(q.x, lo, lists[0], &cnt[0], lane);
        compact1(q.y, lo, lists[0], &cnt[0], lane);
        compact1(q.z, lo, lists[0], &cnt[0], lane);
        compact1(q.w, lo, lists[0], &cnt[0], lane);
    }
    {
        int4 q = make_int4(-1, -1, -1, -1);
        if (tid < NIDX / 4)
            q = reinterpret_cast<const int4*>(proc_idx + (size_t)b * NIDX)[tid];
        compact1(q.x, lo, lists[1], &cnt[1], lane);
        compact1(q.y, lo, lists[1], &cnt[1], lane);
        compact1(q.z, lo, lists[1], &cnt[1], lane);
        compact1(q.w, lo, lists[1], &cnt[1], lane);
    }
    __syncthreads();

    // Phase 2: gather matched rows from the (L2-resident) slice.
    // Waves 0,1 -> diag list; waves 2,3 -> proc list. bf16 row = 256 B =
    // 64 lanes x dword (2 dims/lane), fully coalesced, one row per iteration.
    const unsigned short* __restrict__ sbase = embb + (size_t)lo * D;
    const int h     = wave >> 1;            // which half's list
    const int wpair = wave & 1;
    const int n     = cnt[h];
    const int beg   = (wpair * n) >> 1;
    const int end   = ((wpair + 1) * n) >> 1;
    const int* __restrict__ lst = lists[h];

    float ax = 0.f, ay = 0.f;
    #pragma unroll 4
    for (int i = beg; i < end; ++i) {
        const int rl = lst[i];              // LDS broadcast (wave-uniform)
        const unsigned v =
            reinterpret_cast<const unsigned*>(sbase + (size_t)rl * D)[lane];
        ax += __uint_as_float(v << 16);          // dim 2*lane
        ay += __uint_as_float(v & 0xFFFF0000u);  // dim 2*lane+1
    }
    part[wave][2 * lane]     = ax;
    part[wave][2 * lane + 1] = ay;
    __syncthreads();

    // Phase 3: combine wave pairs, scale by 1/L, accumulate into pooled.
    {
        const int hh = tid >> 7;            // 0 diag, 1 proc
        const int d  = tid & (D - 1);
        const float s = (part[2 * hh][d] + part[2 * hh + 1][d]) * (1.0f / L);
        atomicAdd(&pooled[(size_t)b * TWO_D + hh * D + d], s);
    }
}

// ---- logreg head: out[b,c] = bias[c] + dot(pooled[b,:], W[c,:]) ------------
__global__ __launch_bounds__(128)
void head_kernel(const float* __restrict__ pooled,
                 const float* __restrict__ W,
                 const float* __restrict__ bias,
                 float* __restrict__ out)
{
    __shared__ float x[TWO_D];
    const int b   = blockIdx.x;
    const int tid = threadIdx.x;
    x[tid]       = pooled[(size_t)b * TWO_D + tid];
    x[tid + 128] = pooled[(size_t)b * TWO_D + 128 + tid];
    __syncthreads();

    const float4* __restrict__ wrow =
        reinterpret_cast<const float4*>(W + (size_t)tid * TWO_D);
    const float4* __restrict__ xv = reinterpret_cast<const float4*>(x);
    float s = bias[tid];
    #pragma unroll 16
    for (int k = 0; k < TWO_D / 4; ++k) {
        const float4 w4 = wrow[k];
        const float4 x4 = xv[k];
        s = fmaf(w4.x, x4.x, s);
        s = fmaf(w4.y, x4.y, s);
        s = fmaf(w4.z, x4.z, s);
        s = fmaf(w4.w, x4.w, s);
    }
    out[(size_t)b * NCLASS + tid] = s;
}

// ---- fallback: R3 monolithic bf16 gather (if ws too small for pooled) ------
__global__ __launch_bounds__(256, 4)
void pool_gemm_bf16_kernel(const int* __restrict__ diag_idx,
                           const int* __restrict__ proc_idx,
                           const unsigned short* __restrict__ embb,
                           const float* __restrict__ W,
                           const float* __restrict__ bias,
                           float* __restrict__ out)
{
    __shared__ float4 part4[4][64];
    __shared__ float  x_lds[TWO_D];

    const int b    = blockIdx.x;
    const int tid  = threadIdx.x;
    const int wave = tid >> 6;
    const int lane = tid & 63;

    const int half  = wave >> 1;
    const int chunk = wave & 1;
    const int* __restrict__ idx =
        (half == 0 ? diag_idx : proc_idx) + (size_t)b * NIDX + (size_t)chunk * (NIDX / 2);
    const int2* __restrict__ idx2 = reinterpret_cast<const int2*>(idx);

    const ushort4* __restrict__ emb4 = reinterpret_cast<const ushort4*>(embb);
    const int c = lane & 31;

    float4 acc = make_float4(0.f, 0.f, 0.f, 0.f);
    #pragma unroll 10
    for (int i = 0; i < NIDX / 4; ++i) {
        const int2 p = idx2[i];
        const int  r = (lane & 32) ? p.y : p.x;
        const ushort4 e = emb4[(size_t)r * (D / 4) + c];
        acc.x += __uint_as_float((unsigned int)e.x << 16);
        acc.y += __uint_as_float((unsigned int)e.y << 16);
        acc.z += __uint_as_float((unsigned int)e.z << 16);
        acc.w += __uint_as_float((unsigned int)e.w << 16);
    }
    part4[wave][lane] = acc;
    __syncthreads();

    {
        const int h   = tid >> 7;
        const int rem = tid & 127;
        const int cc  = rem >> 2;
        const int j   = rem & 3;
        const float* p0 = reinterpret_cast<const float*>(&part4[2 * h][cc]);
        const float* p1 = reinterpret_cast<const float*>(&part4[2 * h][cc + 32]);
        const float* p2 = reinterpret_cast<const float*>(&part4[2 * h + 1][cc]);
        const float* p3 = reinterpret_cast<const float*>(&part4[2 * h + 1][cc + 32]);
        x_lds[tid] = (p0[j] + p1[j] + p2[j] + p3[j]) * (1.0f / L);
    }
    __syncthreads();

    if (tid < NCLASS) {
        const float4* __restrict__ wrow =
            reinterpret_cast<const float4*>(W + (size_t)tid * TWO_D);
        const float4* __restrict__ xv = reinterpret_cast<const float4*>(x_lds);
        float s = bias[tid];
        #pragma unroll 8
        for (int k = 0; k < TWO_D / 4; ++k) {
            const float4 w4 = wrow[k];
            const float4 x4 = xv[k];
            s = fmaf(w4.x, x4.x, s);
            s = fmaf(w4.y, x4.y, s);
            s = fmaf(w4.z, x4.z, s);
            s = fmaf(w4.w, x4.w, s);
        }
        out[(size_t)b * NCLASS + tid] = s;
    }
}

// ---- fallback: fp32 gather (if ws can't hold bf16 emb at all) --------------
__global__ __launch_bounds__(256, 4)
void pool_gemm_f32_kernel(const int* __restrict__ diag_idx,
                          const int* __restrict__ proc_idx,
                          const float* __restrict__ emb,
                          const float* __restrict__ W,
                          const float* __restrict__ bias,
                          float* __restrict__ out)
{
    __shared__ float4 part4[4][64];
    __shared__ float  x_lds[TWO_D];

    const int b    = blockIdx.x;
    const int tid  = threadIdx.x;
    const int wave = tid >> 6;
    const int lane = tid & 63;

    const int half  = wave >> 1;
    const int chunk = wave & 1;
    const int* __restrict__ idx =
        (half == 0 ? diag_idx : proc_idx) + (size_t)b * NIDX + (size_t)chunk * (NIDX / 2);
    const int2* __restrict__ idx2 = reinterpret_cast<const int2*>(idx);

    const float4* __restrict__ emb4 = reinterpret_cast<const float4*>(emb);
    const int c = lane & 31;

    float4 acc = make_float4(0.f, 0.f, 0.f, 0.f);
    #pragma unroll 5
    for (int i = 0; i < NIDX / 4; ++i) {
        const int2 p = idx2[i];
        const int  r = (lane & 32) ? p.y : p.x;
        const float4 e = emb4[(size_t)r * (D / 4) + c];
        acc.x += e.x; acc.y += e.y; acc.z += e.z; acc.w += e.w;
    }
    part4[wave][lane] = acc;
    __syncthreads();

    {
        const int h   = tid >> 7;
        const int rem = tid & 127;
        const int cc  = rem >> 2;
        const int j   = rem & 3;
        const float* p0 = reinterpret_cast<const float*>(&part4[2 * h][cc]);
        const float* p1 = reinterpret_cast<const float*>(&part4[2 * h][cc + 32]);
        const float* p2 = reinterpret_cast<const float*>(&part4[2 * h + 1][cc]);
        const float* p3 = reinterpret_cast<const float*>(&part4[2 * h + 1][cc + 32]);
        x_lds[tid] = (p0[j] + p1[j] + p2[j] + p3[j]) * (1.0f / L);
    }
    __syncthreads();

    if (tid < NCLASS) {
        const float4* __restrict__ wrow =
            reinterpret_cast<const float4*>(W + (size_t)tid * TWO_D);
        const float4* __restrict__ xv = reinterpret_cast<const float4*>(x_lds);
        float s = bias[tid];
        #pragma unroll 8
        for (int k = 0; k < TWO_D / 4; ++k) {
            const float4 w4 = wrow[k];
            const float4 x4 = xv[k];
            s = fmaf(w4.x, x4.x, s);
            s = fmaf(w4.y, x4.y, s);
            s = fmaf(w4.z, x4.z, s);
            s = fmaf(w4.w, x4.w, s);
        }
        out[(size_t)b * NCLASS + tid] = s;
    }
}

extern "C" void kernel_launch(void* const* d_in, const int* in_sizes, int n_in,
                              void* d_out, int out_size, void* d_ws, size_t ws_size,
                              hipStream_t stream)
{
    const int*   diag = (const int*)d_in[0];
    const int*   proc = (const int*)d_in[1];
    const float* emb  = (const float*)d_in[2];
    const float* W    = (const float*)d_in[3];
    const float* bias = (const float*)d_in[4];
    float*       out  = (float*)d_out;

    const size_t emb_bf_bytes = (size_t)VOCAB * D * sizeof(unsigned short); // 25.6 MB
    const size_t pooled_bytes = (size_t)B * TWO_D * sizeof(float);          // 2 MB

    if (ws_size >= emb_bf_bytes + pooled_bytes) {
        unsigned short* embb   = (unsigned short*)d_ws;
        float*          pooled = (float*)((char*)d_ws + emb_bf_bytes);

        convert_kernel<<<(VOCAB * D / 4) / 256, 256, 0, stream>>>(emb, embb);
        hipMemsetAsync(pooled, 0, pooled_bytes, stream);
        slice_pool_kernel<<<B * NSLICE, 256, 0, stream>>>(diag, proc, embb, pooled);
        head_kernel<<<B, 128, 0, stream>>>(pooled, W, bias, out);
    } else if (ws_size >= emb_bf_bytes) {
        unsigned short* embb = (unsigned short*)d_ws;
        convert_kernel<<<(VOCAB * D / 4) / 256, 256, 0, stream>>>(emb, embb);
        pool_gemm_bf16_kernel<<<B, 256, 0, stream>>>(diag, proc, embb, W, bias, out);
    } else {
        pool_gemm_f32_kernel<<<B, 256, 0, stream>>>(diag, proc, emb, W, bias, out);
    }
}

// Round 5
// 188.486 us; speedup vs baseline: 2.0001x; 1.1616x over previous
//
#include <hip/hip_runtime.h>

// EmbeddedLogRegClassifier: fused gather-pool + logreg head.
// pooled[b, d]   = (1/L) * sum_{v,l} emb[diag_idx[b,v,l], d]
// pooled[b, D+d] = (1/L) * sum_{v,l} emb[proc_idx[b,v,l], d]
// out[b, c]      = bias[c] + sum_k pooled[b, k] * W[c, k]
//
// R5 structure:
//   k1 (fused prep):  emb fp32 -> bf16 in XCD-sliced layout [8][12501][128]
//                     (row 12500 of each slice = zeros, used as pad sentinel),
//                     + per-sample counting-sort of indices by slice
//                     (ushort local row ids + prefix offsets), + zero pooled.
//   k2 (slice_pool):  block (b, slice): gather its pre-sorted in-slice rows
//                     from the 3.2 MB L2-resident slice, 4 rows/wave-iter via
//                     dwordx4 (8 dims/lane), atomicAdd partials into pooled.
//   k3 (head):        out = pooled @ W^T + b.

constexpr int B      = 2048;
constexpr int V      = 50;
constexpr int L      = 20;
constexpr int D      = 128;
constexpr int NIDX   = V * L;     // 1000 indices per (sample, half)
constexpr int NCLASS = 128;
constexpr int TWO_D  = 2 * D;     // 256
constexpr int VOCAB  = 100000;
constexpr int NSLICE = 8;
constexpr int SLICE_ROWS = VOCAB / NSLICE;          // 12500
constexpr int SROWS_P    = SLICE_ROWS + 1;          // +1 zero row (pad sentinel)

__device__ __forceinline__ unsigned short f2bf_rne(float f) {
    unsigned int u = __float_as_uint(f);
    unsigned int r = (u + 0x7FFFu + ((u >> 16) & 1u)) >> 16;   // round-nearest-even
    return (unsigned short)r;
}
__device__ __forceinline__ float uif(unsigned int u) { return __uint_as_float(u); }

// ---------------- k1: fused convert + zero-rows + bucket + pooled-zero ------
// grid = 12500 (convert) + 1 (zero rows) + 2048 (bucket) blocks of 256.
__global__ __launch_bounds__(256)
void prep_kernel(const float* __restrict__ emb,
                 const int* __restrict__ diag_idx,
                 const int* __restrict__ proc_idx,
                 unsigned short* __restrict__ embb,   // [8][12501][128]
                 unsigned short* __restrict__ sorted, // [B][2][1000]
                 int* __restrict__ offs,              // [B][2][9]
                 float* __restrict__ pooled)          // [B][256]
{
    const int bid = blockIdx.x;
    const int tid = threadIdx.x;

    if (bid < 12500) {
        // convert: one float4 (= ushort4 out) per thread
        const int i4 = bid * 256 + tid;          // [0, 3.2M)
        const int r  = i4 >> 5;                  // 32 float4 per row
        const int s  = r / SLICE_ROWS;           // compiler magic-mul
        const float4 v = reinterpret_cast<const float4*>(emb)[i4];
        ushort4 o;
        o.x = f2bf_rne(v.x); o.y = f2bf_rne(v.y);
        o.z = f2bf_rne(v.z); o.w = f2bf_rne(v.w);
        reinterpret_cast<ushort4*>(embb)[i4 + s * 32] = o;  // sliced layout
        return;
    }
    if (bid == 12500) {
        // zero row 12500 of each slice: 8 rows x 32 ushort4
        const int s = tid >> 5, u = tid & 31;
        reinterpret_cast<ushort4*>(embb)[((size_t)s * SROWS_P + SLICE_ROWS) * 32 + u] =
            make_ushort4(0, 0, 0, 0);
        return;
    }

    // bucket: one sample per block
    const int b = bid - 12501;

    __shared__ int cnt[2][NSLICE];
    __shared__ int woff[2][NSLICE];
    __shared__ int offsS[2][NSLICE + 1];
    __shared__ unsigned short sl[2][NIDX];

    if (tid < 16) cnt[tid >> 3][tid & 7] = 0;
    __syncthreads();

    int4 qd = make_int4(0, 0, 0, 0), qp = make_int4(0, 0, 0, 0);
    const bool act = tid < NIDX / 4;
    if (act) {
        qd = reinterpret_cast<const int4*>(diag_idx + (size_t)b * NIDX)[tid];
        qp = reinterpret_cast<const int4*>(proc_idx + (size_t)b * NIDX)[tid];
        atomicAdd(&cnt[0][qd.x / SLICE_ROWS], 1);
        atomicAdd(&cnt[0][qd.y / SLICE_ROWS], 1);
        atomicAdd(&cnt[0][qd.z / SLICE_ROWS], 1);
        atomicAdd(&cnt[0][qd.w / SLICE_ROWS], 1);
        atomicAdd(&cnt[1][qp.x / SLICE_ROWS], 1);
        atomicAdd(&cnt[1][qp.y / SLICE_ROWS], 1);
        atomicAdd(&cnt[1][qp.z / SLICE_ROWS], 1);
        atomicAdd(&cnt[1][qp.w / SLICE_ROWS], 1);
    }
    __syncthreads();

    if (tid < 2) {
        int run = 0;
        for (int k = 0; k < NSLICE; ++k) {
            offsS[tid][k] = run;
            woff[tid][k]  = run;
            run += cnt[tid][k];
        }
        offsS[tid][NSLICE] = run;   // == 1000
    }
    __syncthreads();

    if (act) {
        int s, p;
        s = qd.x / SLICE_ROWS; p = atomicAdd(&woff[0][s], 1); sl[0][p] = (unsigned short)(qd.x - s * SLICE_ROWS);
        s = qd.y / SLICE_ROWS; p = atomicAdd(&woff[0][s], 1); sl[0][p] = (unsigned short)(qd.y - s * SLICE_ROWS);
        s = qd.z / SLICE_ROWS; p = atomicAdd(&woff[0][s], 1); sl[0][p] = (unsigned short)(qd.z - s * SLICE_ROWS);
        s = qd.w / SLICE_ROWS; p = atomicAdd(&woff[0][s], 1); sl[0][p] = (unsigned short)(qd.w - s * SLICE_ROWS);
        s = qp.x / SLICE_ROWS; p = atomicAdd(&woff[1][s], 1); sl[1][p] = (unsigned short)(qp.x - s * SLICE_ROWS);
        s = qp.y / SLICE_ROWS; p = atomicAdd(&woff[1][s], 1); sl[1][p] = (unsigned short)(qp.y - s * SLICE_ROWS);
        s = qp.z / SLICE_ROWS; p = atomicAdd(&woff[1][s], 1); sl[1][p] = (unsigned short)(qp.z - s * SLICE_ROWS);
        s = qp.w / SLICE_ROWS; p = atomicAdd(&woff[1][s], 1); sl[1][p] = (unsigned short)(qp.w - s * SLICE_ROWS);
    }
    __syncthreads();

    // write sorted lists (as u32 pairs) + offsets + zero pooled
    unsigned int* so = reinterpret_cast<unsigned int*>(sorted + (size_t)b * 2 * NIDX);
    for (int t = tid; t < NIDX; t += 256) {           // 1000 u32s: [h=0 500][h=1 500]
        const int h = t / (NIDX / 2), i = t % (NIDX / 2);
        so[t] = (unsigned int)sl[h][2 * i] | ((unsigned int)sl[h][2 * i + 1] << 16);
    }
    if (tid < 2 * (NSLICE + 1))
        offs[b * 2 * (NSLICE + 1) + tid] = offsS[tid / (NSLICE + 1)][tid % (NSLICE + 1)];
    pooled[(size_t)b * TWO_D + tid] = 0.0f;
}

// ---------------- k2: sliced gather-pool ------------------------------------
__global__ __launch_bounds__(256, 4)
void slice_pool_kernel(const unsigned short* __restrict__ embb,
                       const unsigned short* __restrict__ sorted,
                       const int* __restrict__ offs,
                       float* __restrict__ pooled)
{
    __shared__ unsigned short lls[2][NIDX + 8];
    __shared__ float part[4][64][8];

    const int slice = blockIdx.x & (NSLICE - 1);   // consecutive bids -> XCDs
    const int b     = blockIdx.x >> 3;
    const int tid   = threadIdx.x;
    const int lane  = tid & 63;
    const int wave  = tid >> 6;

    const int* ob  = offs + b * 2 * (NSLICE + 1);
    const int beg0 = ob[slice],              n0 = ob[slice + 1] - ob[slice];
    const int beg1 = ob[NSLICE + 1 + slice], n1 = ob[NSLICE + 2 + slice] - ob[NSLICE + 1 + slice];

    // stage this block's two list segments into LDS, pad to x8 with sentinel
    const unsigned short* s16 = sorted + (size_t)b * 2 * NIDX;
    for (int i = tid; i < n0; i += 256) lls[0][i] = s16[beg0 + i];
    for (int i = tid; i < n1; i += 256) lls[1][i] = s16[NIDX + beg1 + i];
    if (tid < ((8 - (n0 & 7)) & 7)) lls[0][n0 + tid] = (unsigned short)SLICE_ROWS;
    if (tid < ((8 - (n1 & 7)) & 7)) lls[1][n1 + tid] = (unsigned short)SLICE_ROWS;
    __syncthreads();

    // gather: waves 0,1 -> diag; 2,3 -> proc. 4 rows per iter, 16 lanes/row,
    // 8 dims/lane via dwordx4. Sentinel rows read the zero row -> add 0.
    const int h  = wave >> 1;
    const int w2 = wave & 1;
    const int sub = lane >> 4;          // which of the 4 rows in this batch
    const int c   = lane & 15;          // 16B chunk within the row
    const int n   = h ? n1 : n0;
    const int n_pad = (n + 7) & ~7;

    const uint4* __restrict__ sbase =
        reinterpret_cast<const uint4*>(embb + (size_t)slice * SROWS_P * D);
    const unsigned short* __restrict__ lb = &lls[h][0];

    float a0 = 0.f, a1 = 0.f, a2 = 0.f, a3 = 0.f,
          a4 = 0.f, a5 = 0.f, a6 = 0.f, a7 = 0.f;
    #pragma unroll 2
    for (int i = w2 * 4; i < n_pad; i += 8) {
        const int rl = (int)lb[i + sub];          // 16-lane-group broadcast
        const uint4 e = sbase[rl * 16 + c];       // 16 uint4 per 256B row
        a0 += uif(e.x << 16); a1 += uif(e.x & 0xFFFF0000u);
        a2 += uif(e.y << 16); a3 += uif(e.y & 0xFFFF0000u);
        a4 += uif(e.z << 16); a5 += uif(e.z & 0xFFFF0000u);
        a6 += uif(e.w << 16); a7 += uif(e.w & 0xFFFF0000u);
    }
    float* pw = &part[wave][lane][0];
    pw[0] = a0; pw[1] = a1; pw[2] = a2; pw[3] = a3;
    pw[4] = a4; pw[5] = a5; pw[6] = a6; pw[7] = a7;
    __syncthreads();

    // reduce: dim = c*8 + j gets contributions from subs 0..3 x wave-pair
    {
        const int hh  = tid >> 7;           // 0 diag, 1 proc
        const int dim = tid & 127;
        const int cc  = dim >> 3;
        const int j   = dim & 7;
        float s = 0.f;
        #pragma unroll
        for (int wp = 0; wp < 2; ++wp)
            #pragma unroll
            for (int sb = 0; sb < 4; ++sb)
                s += part[2 * hh + wp][sb * 16 + cc][j];
        atomicAdd(&pooled[(size_t)b * TWO_D + hh * D + dim], s * (1.0f / L));
    }
}

// ---------------- k3: logreg head -------------------------------------------
__global__ __launch_bounds__(128)
void head_kernel(const float* __restrict__ pooled,
                 const float* __restrict__ W,
                 const float* __restrict__ bias,
                 float* __restrict__ out)
{
    __shared__ float x[TWO_D];
    const int b   = blockIdx.x;
    const int tid = threadIdx.x;
    x[tid]       = pooled[(size_t)b * TWO_D + tid];
    x[tid + 128] = pooled[(size_t)b * TWO_D + 128 + tid];
    __syncthreads();

    const float4* __restrict__ wrow =
        reinterpret_cast<const float4*>(W + (size_t)tid * TWO_D);
    const float4* __restrict__ xv = reinterpret_cast<const float4*>(x);
    float s = bias[tid];
    #pragma unroll 16
    for (int k = 0; k < TWO_D / 4; ++k) {
        const float4 w4 = wrow[k];
        const float4 x4 = xv[k];
        s = fmaf(w4.x, x4.x, s);
        s = fmaf(w4.y, x4.y, s);
        s = fmaf(w4.z, x4.z, s);
        s = fmaf(w4.w, x4.w, s);
    }
    out[(size_t)b * NCLASS + tid] = s;
}

// ---------------- fallbacks (ws too small) ----------------------------------
__global__ __launch_bounds__(256)
void convert_flat_kernel(const float* __restrict__ emb, unsigned short* __restrict__ o)
{
    const int i = blockIdx.x * 256 + threadIdx.x;
    const float4 v = reinterpret_cast<const float4*>(emb)[i];
    ushort4 u;
    u.x = f2bf_rne(v.x); u.y = f2bf_rne(v.y);
    u.z = f2bf_rne(v.z); u.w = f2bf_rne(v.w);
    reinterpret_cast<ushort4*>(o)[i] = u;
}

__global__ __launch_bounds__(256, 4)
void pool_gemm_bf16_kernel(const int* __restrict__ diag_idx,
                           const int* __restrict__ proc_idx,
                           const unsigned short* __restrict__ embb,
                           const float* __restrict__ W,
                           const float* __restrict__ bias,
                           float* __restrict__ out)
{
    __shared__ float4 part4[4][64];
    __shared__ float  x_lds[TWO_D];

    const int b    = blockIdx.x;
    const int tid  = threadIdx.x;
    const int wave = tid >> 6;
    const int lane = tid & 63;

    const int half  = wave >> 1;
    const int chunk = wave & 1;
    const int* __restrict__ idx =
        (half == 0 ? diag_idx : proc_idx) + (size_t)b * NIDX + (size_t)chunk * (NIDX / 2);
    const int2* __restrict__ idx2 = reinterpret_cast<const int2*>(idx);

    const ushort4* __restrict__ emb4 = reinterpret_cast<const ushort4*>(embb);
    const int c = lane & 31;

    float4 acc = make_float4(0.f, 0.f, 0.f, 0.f);
    #pragma unroll 10
    for (int i = 0; i < NIDX / 4; ++i) {
        const int2 p = idx2[i];
        const int  r = (lane & 32) ? p.y : p.x;
        const ushort4 e = emb4[(size_t)r * (D / 4) + c];
        acc.x += uif((unsigned int)e.x << 16);
        acc.y += uif((unsigned int)e.y << 16);
        acc.z += uif((unsigned int)e.z << 16);
        acc.w += uif((unsigned int)e.w << 16);
    }
    part4[wave][lane] = acc;
    __syncthreads();

    {
        const int h   = tid >> 7;
        const int rem = tid & 127;
        const int cc  = rem >> 2;
        const int j   = rem & 3;
        const float* p0 = reinterpret_cast<const float*>(&part4[2 * h][cc]);
        const float* p1 = reinterpret_cast<const float*>(&part4[2 * h][cc + 32]);
        const float* p2 = reinterpret_cast<const float*>(&part4[2 * h + 1][cc]);
        const float* p3 = reinterpret_cast<const float*>(&part4[2 * h + 1][cc + 32]);
        x_lds[tid] = (p0[j] + p1[j] + p2[j] + p3[j]) * (1.0f / L);
    }
    __syncthreads();

    if (tid < NCLASS) {
        const float4* __restrict__ wrow =
            reinterpret_cast<const float4*>(W + (size_t)tid * TWO_D);
        const float4* __restrict__ xv = reinterpret_cast<const float4*>(x_lds);
        float s = bias[tid];
        #pragma unroll 8
        for (int k = 0; k < TWO_D / 4; ++k) {
            const float4 w4 = wrow[k];
            const float4 x4 = xv[k];
            s = fmaf(w4.x, x4.x, s);
            s = fmaf(w4.y, x4.y, s);
            s = fmaf(w4.z, x4.z, s);
            s = fmaf(w4.w, x4.w, s);
        }
        out[(size_t)b * NCLASS + tid] = s;
    }
}

__global__ __launch_bounds__(256, 4)
void pool_gemm_f32_kernel(const int* __restrict__ diag_idx,
                          const int* __restrict__ proc_idx,
                          const float* __restrict__ emb,
                          const float* __restrict__ W,
                          const float* __restrict__ bias,
                          float* __restrict__ out)
{
    __shared__ float4 part4[4][64];
    __shared__ float  x_lds[TWO_D];

    const int b    = blockIdx.x;
    const int tid  = threadIdx.x;
    const int wave = tid >> 6;
    const int lane = tid & 63;

    const int half  = wave >> 1;
    const int chunk = wave & 1;
    const int* __restrict__ idx =
        (half == 0 ? diag_idx : proc_idx) + (size_t)b * NIDX + (size_t)chunk * (NIDX / 2);
    const int2* __restrict__ idx2 = reinterpret_cast<const int2*>(idx);

    const float4* __restrict__ emb4 = reinterpret_cast<const float4*>(emb);
    const int c = lane & 31;

    float4 acc = make_float4(0.f, 0.f, 0.f, 0.f);
    #pragma unroll 5
    for (int i = 0; i < NIDX / 4; ++i) {
        const int2 p = idx2[i];
        const int  r = (lane & 32) ? p.y : p.x;
        const float4 e = emb4[(size_t)r * (D / 4) + c];
        acc.x += e.x; acc.y += e.y; acc.z += e.z; acc.w += e.w;
    }
    part4[wave][lane] = acc;
    __syncthreads();

    {
        const int h   = tid >> 7;
        const int rem = tid & 127;
        const int cc  = rem >> 2;
        const int j   = rem & 3;
        const float* p0 = reinterpret_cast<const float*>(&part4[2 * h][cc]);
        const float* p1 = reinterpret_cast<const float*>(&part4[2 * h][cc + 32]);
        const float* p2 = reinterpret_cast<const float*>(&part4[2 * h + 1][cc]);
        const float* p3 = reinterpret_cast<const float*>(&part4[2 * h + 1][cc + 32]);
        x_lds[tid] = (p0[j] + p1[j] + p2[j] + p3[j]) * (1.0f / L);
    }
    __syncthreads();

    if (tid < NCLASS) {
        const float4* __restrict__ wrow =
            reinterpret_cast<const float4*>(W + (size_t)tid * TWO_D);
        const float4* __restrict__ xv = reinterpret_cast<const float4*>(x_lds);
        float s = bias[tid];
        #pragma unroll 8
        for (int k = 0; k < TWO_D / 4; ++k) {
            const float4 w4 = wrow[k];
            const float4 x4 = xv[k];
            s = fmaf(w4.x, x4.x, s);
            s = fmaf(w4.y, x4.y, s);
            s = fmaf(w4.z, x4.z, s);
            s = fmaf(w4.w, x4.w, s);
        }
        out[(size_t)b * NCLASS + tid] = s;
    }
}

extern "C" void kernel_launch(void* const* d_in, const int* in_sizes, int n_in,
                              void* d_out, int out_size, void* d_ws, size_t ws_size,
                              hipStream_t stream)
{
    const int*   diag = (const int*)d_in[0];
    const int*   proc = (const int*)d_in[1];
    const float* emb  = (const float*)d_in[2];
    const float* W    = (const float*)d_in[3];
    const float* bias = (const float*)d_in[4];
    float*       out  = (float*)d_out;

    const size_t embb_bytes   = (size_t)NSLICE * SROWS_P * D * sizeof(unsigned short); // 25.602 MB
    const size_t sorted_bytes = (size_t)B * 2 * NIDX * sizeof(unsigned short);         // 8.192 MB
    const size_t offs_bytes   = (size_t)B * 2 * (NSLICE + 1) * sizeof(int);            // 147 KB
    const size_t pooled_bytes = (size_t)B * TWO_D * sizeof(float);                     // 2 MB
    const size_t need = embb_bytes + sorted_bytes + offs_bytes + pooled_bytes;

    const size_t emb_flat_bytes = (size_t)VOCAB * D * sizeof(unsigned short);          // 25.6 MB

    if (ws_size >= need) {
        char* p = (char*)d_ws;
        unsigned short* embb   = (unsigned short*)p;              p += embb_bytes;
        unsigned short* sorted = (unsigned short*)p;              p += sorted_bytes;
        int*            offs   = (int*)p;                         p += offs_bytes;
        float*          pooled = (float*)p;

        prep_kernel<<<12501 + B, 256, 0, stream>>>(emb, diag, proc,
                                                   embb, sorted, offs, pooled);
        slice_pool_kernel<<<B * NSLICE, 256, 0, stream>>>(embb, sorted, offs, pooled);
        head_kernel<<<B, 128, 0, stream>>>(pooled, W, bias, out);
    } else if (ws_size >= emb_flat_bytes) {
        unsigned short* embb = (unsigned short*)d_ws;
        convert_flat_kernel<<<(VOCAB * D / 4) / 256, 256, 0, stream>>>(emb, embb);
        pool_gemm_bf16_kernel<<<B, 256, 0, stream>>>(diag, proc, embb, W, bias, out);
    } else {
        pool_gemm_f32_kernel<<<B, 256, 0, stream>>>(diag, proc, emb, W, bias, out);
    }
}

// Round 7
// 180.497 us; speedup vs baseline: 2.0887x; 1.0443x over previous
//
#include <hip/hip_runtime.h>

// EmbeddedLogRegClassifier: fused gather-pool + logreg head.
// pooled[b, d]   = (1/L) * sum_{v,l} emb[diag_idx[b,v,l], d]
// pooled[b, D+d] = (1/L) * sum_{v,l} emb[proc_idx[b,v,l], d]
// out[b, c]      = bias[c] + sum_k pooled[b, k] * W[c, k]
//
// R6b: fp16 table + v_pk_add_f16 accumulation (1 VALU per dword vs 4 for the
// bf16 unpack+add), padded LDS partials (conflict-free), unroll 4.
//   k1 prep:   emb fp32 -> fp16 (cvt_pkrtz) into XCD-sliced [8][12501][128]
//              (row 12500 per slice = zeros, pad sentinel) + per-sample
//              counting-sort of indices by slice + zero pooled.
//   k2 slice:  block (b, slice): gather pre-sorted in-slice rows from the
//              3.2 MB L2-resident slice, 4 rows/wave-iter via dwordx4,
//              pk_add_f16 accumulate, widen to fp32, atomicAdd into pooled.
//   k3 head:   out = pooled @ W^T + b.

typedef _Float16 h2 __attribute__((ext_vector_type(2)));

constexpr int B      = 2048;
constexpr int V      = 50;
constexpr int L      = 20;
constexpr int D      = 128;
constexpr int NIDX   = V * L;     // 1000 indices per (sample, half)
constexpr int NCLASS = 128;
constexpr int TWO_D  = 2 * D;     // 256
constexpr int VOCAB  = 100000;
constexpr int NSLICE = 8;
constexpr int SLICE_ROWS = VOCAB / NSLICE;          // 12500
constexpr int SROWS_P    = SLICE_ROWS + 1;          // +1 zero row (pad sentinel)

__device__ __forceinline__ unsigned short f2bf_rne(float f) {
    unsigned int u = __float_as_uint(f);
    unsigned int r = (u + 0x7FFFu + ((u >> 16) & 1u)) >> 16;
    return (unsigned short)r;
}
__device__ __forceinline__ float uif(unsigned int u) { return __uint_as_float(u); }

__device__ __forceinline__ unsigned int pk_f16(float a, float b) {
    // v_cvt_pkrtz_f16_f32: returns __fp16x2; reinterpret as u32
    return __builtin_bit_cast(unsigned int, __builtin_amdgcn_cvt_pkrtz(a, b));
}

// ---------------- k1: fused convert + zero-rows + bucket + pooled-zero ------
// grid = 12500 (convert) + 1 (zero rows) + 2048 (bucket) blocks of 256.
__global__ __launch_bounds__(256)
void prep_kernel(const float* __restrict__ emb,
                 const int* __restrict__ diag_idx,
                 const int* __restrict__ proc_idx,
                 unsigned short* __restrict__ embb,   // fp16 [8][12501][128]
                 unsigned short* __restrict__ sorted, // [B][2][1000]
                 int* __restrict__ offs,              // [B][2][9]
                 float* __restrict__ pooled)          // [B][256]
{
    const int bid = blockIdx.x;
    const int tid = threadIdx.x;

    if (bid < 12500) {
        // convert: one float4 -> one uint2 (4 fp16) per thread
        const int i4 = bid * 256 + tid;          // [0, 3.2M) 8B-units
        const int r  = i4 >> 5;                  // 32 units per row
        const int s  = r / SLICE_ROWS;
        const float4 v = reinterpret_cast<const float4*>(emb)[i4];
        uint2 o;
        o.x = pk_f16(v.x, v.y);
        o.y = pk_f16(v.z, v.w);
        reinterpret_cast<uint2*>(embb)[i4 + s * 32] = o;  // sliced layout
        return;
    }
    if (bid == 12500) {
        // zero row 12500 of each slice: 8 rows x 32 uint2
        const int s = tid >> 5, u = tid & 31;
        reinterpret_cast<uint2*>(embb)[((size_t)s * SROWS_P + SLICE_ROWS) * 32 + u] =
            make_uint2(0u, 0u);
        return;
    }

    // bucket: one sample per block
    const int b = bid - 12501;

    __shared__ int cnt[2][NSLICE];
    __shared__ int woff[2][NSLICE];
    __shared__ int offsS[2][NSLICE + 1];
    __shared__ unsigned short sl[2][NIDX];

    if (tid < 16) cnt[tid >> 3][tid & 7] = 0;
    __syncthreads();

    int4 qd = make_int4(0, 0, 0, 0), qp = make_int4(0, 0, 0, 0);
    const bool act = tid < NIDX / 4;
    if (act) {
        qd = reinterpret_cast<const int4*>(diag_idx + (size_t)b * NIDX)[tid];
        qp = reinterpret_cast<const int4*>(proc_idx + (size_t)b * NIDX)[tid];
        atomicAdd(&cnt[0][qd.x / SLICE_ROWS], 1);
        atomicAdd(&cnt[0][qd.y / SLICE_ROWS], 1);
        atomicAdd(&cnt[0][qd.z / SLICE_ROWS], 1);
        atomicAdd(&cnt[0][qd.w / SLICE_ROWS], 1);
        atomicAdd(&cnt[1][qp.x / SLICE_ROWS], 1);
        atomicAdd(&cnt[1][qp.y / SLICE_ROWS], 1);
        atomicAdd(&cnt[1][qp.z / SLICE_ROWS], 1);
        atomicAdd(&cnt[1][qp.w / SLICE_ROWS], 1);
    }
    __syncthreads();

    if (tid < 2) {
        int run = 0;
        for (int k = 0; k < NSLICE; ++k) {
            offsS[tid][k] = run;
            woff[tid][k]  = run;
            run += cnt[tid][k];
        }
        offsS[tid][NSLICE] = run;   // == 1000
    }
    __syncthreads();

    if (act) {
        int s, p;
        s = qd.x / SLICE_ROWS; p = atomicAdd(&woff[0][s], 1); sl[0][p] = (unsigned short)(qd.x - s * SLICE_ROWS);
        s = qd.y / SLICE_ROWS; p = atomicAdd(&woff[0][s], 1); sl[0][p] = (unsigned short)(qd.y - s * SLICE_ROWS);
        s = qd.z / SLICE_ROWS; p = atomicAdd(&woff[0][s], 1); sl[0][p] = (unsigned short)(qd.z - s * SLICE_ROWS);
        s = qd.w / SLICE_ROWS; p = atomicAdd(&woff[0][s], 1); sl[0][p] = (unsigned short)(qd.w - s * SLICE_ROWS);
        s = qp.x / SLICE_ROWS; p = atomicAdd(&woff[1][s], 1); sl[1][p] = (unsigned short)(qp.x - s * SLICE_ROWS);
        s = qp.y / SLICE_ROWS; p = atomicAdd(&woff[1][s], 1); sl[1][p] = (unsigned short)(qp.y - s * SLICE_ROWS);
        s = qp.z / SLICE_ROWS; p = atomicAdd(&woff[1][s], 1); sl[1][p] = (unsigned short)(qp.z - s * SLICE_ROWS);
        s = qp.w / SLICE_ROWS; p = atomicAdd(&woff[1][s], 1); sl[1][p] = (unsigned short)(qp.w - s * SLICE_ROWS);
    }
    __syncthreads();

    unsigned int* so = reinterpret_cast<unsigned int*>(sorted + (size_t)b * 2 * NIDX);
    for (int t = tid; t < NIDX; t += 256) {           // 1000 u32 pairs
        const int h = t / (NIDX / 2), i = t % (NIDX / 2);
        so[t] = (unsigned int)sl[h][2 * i] | ((unsigned int)sl[h][2 * i + 1] << 16);
    }
    if (tid < 2 * (NSLICE + 1))
        offs[b * 2 * (NSLICE + 1) + tid] = offsS[tid / (NSLICE + 1)][tid % (NSLICE + 1)];
    pooled[(size_t)b * TWO_D + tid] = 0.0f;
}

// ---------------- k2: sliced gather-pool (fp16 pk_add) ----------------------
__global__ __launch_bounds__(256, 4)
void slice_pool_kernel(const unsigned short* __restrict__ embb,
                       const unsigned short* __restrict__ sorted,
                       const int* __restrict__ offs,
                       float* __restrict__ pooled)
{
    __shared__ unsigned short lls[2][NIDX + 8];
    __shared__ float part[4][64][9];   // pad 8->9: conflict-free b32 writes

    const int slice = blockIdx.x & (NSLICE - 1);   // consecutive bids -> XCDs
    const int b     = blockIdx.x >> 3;
    const int tid   = threadIdx.x;
    const int lane  = tid & 63;
    const int wave  = tid >> 6;

    const int* ob  = offs + b * 2 * (NSLICE + 1);
    const int beg0 = ob[slice],              n0 = ob[slice + 1] - ob[slice];
    const int beg1 = ob[NSLICE + 1 + slice], n1 = ob[NSLICE + 2 + slice] - ob[NSLICE + 1 + slice];

    // stage this block's two list segments into LDS, pad to x8 with sentinel
    const unsigned short* s16 = sorted + (size_t)b * 2 * NIDX;
    for (int i = tid; i < n0; i += 256) lls[0][i] = s16[beg0 + i];
    for (int i = tid; i < n1; i += 256) lls[1][i] = s16[NIDX + beg1 + i];
    if (tid < ((8 - (n0 & 7)) & 7)) lls[0][n0 + tid] = (unsigned short)SLICE_ROWS;
    if (tid < ((8 - (n1 & 7)) & 7)) lls[1][n1 + tid] = (unsigned short)SLICE_ROWS;
    __syncthreads();

    // gather: waves 0,1 -> diag; 2,3 -> proc. 4 rows per iter, 16 lanes/row,
    // 8 dims/lane via dwordx4; v_pk_add_f16 accumulates 2 dims/instruction.
    const int h   = wave >> 1;
    const int w2  = wave & 1;
    const int sub = lane >> 4;          // which of the 4 rows in this batch
    const int c   = lane & 15;          // 16B chunk within the row
    const int n   = h ? n1 : n0;
    const int n_pad = (n + 7) & ~7;

    const uint4* __restrict__ sbase =
        reinterpret_cast<const uint4*>(embb + (size_t)slice * SROWS_P * D);
    const unsigned short* __restrict__ lb = &lls[h][0];

    h2 acc0 = {0, 0}, acc1 = {0, 0}, acc2 = {0, 0}, acc3 = {0, 0};
    #pragma unroll 4
    for (int i = w2 * 4; i < n_pad; i += 8) {
        const int rl = (int)lb[i + sub];          // 16-lane-group broadcast
        const uint4 e = sbase[rl * 16 + c];       // 16 uint4 per 256B row
        acc0 += __builtin_bit_cast(h2, e.x);      // v_pk_add_f16
        acc1 += __builtin_bit_cast(h2, e.y);
        acc2 += __builtin_bit_cast(h2, e.z);
        acc3 += __builtin_bit_cast(h2, e.w);
    }
    // widen per-lane partials (<=~32 adds each, fp16-safe) to fp32
    float* pw = &part[wave][lane][0];
    pw[0] = (float)acc0.x; pw[1] = (float)acc0.y;
    pw[2] = (float)acc1.x; pw[3] = (float)acc1.y;
    pw[4] = (float)acc2.x; pw[5] = (float)acc2.y;
    pw[6] = (float)acc3.x; pw[7] = (float)acc3.y;
    __syncthreads();

    // reduce: dim = cc*8 + j over subs 0..3 x wave-pair
    {
        const int hh  = tid >> 7;           // 0 diag, 1 proc
        const int dim = tid & 127;
        const int cc  = dim >> 3;
        const int j   = dim & 7;
        float s = 0.f;
        #pragma unroll
        for (int wp = 0; wp < 2; ++wp)
            #pragma unroll
            for (int sb = 0; sb < 4; ++sb)
                s += part[2 * hh + wp][sb * 16 + cc][j];
        atomicAdd(&pooled[(size_t)b * TWO_D + hh * D + dim], s * (1.0f / L));
    }
}

// ---------------- k3: logreg head -------------------------------------------
__global__ __launch_bounds__(128)
void head_kernel(const float* __restrict__ pooled,
                 const float* __restrict__ W,
                 const float* __restrict__ bias,
                 float* __restrict__ out)
{
    __shared__ float x[TWO_D];
    const int b   = blockIdx.x;
    const int tid = threadIdx.x;
    x[tid]       = pooled[(size_t)b * TWO_D + tid];
    x[tid + 128] = pooled[(size_t)b * TWO_D + 128 + tid];
    __syncthreads();

    const float4* __restrict__ wrow =
        reinterpret_cast<const float4*>(W + (size_t)tid * TWO_D);
    const float4* __restrict__ xv = reinterpret_cast<const float4*>(x);
    float s = bias[tid];
    #pragma unroll 16
    for (int k = 0; k < TWO_D / 4; ++k) {
        const float4 w4 = wrow[k];
        const float4 x4 = xv[k];
        s = fmaf(w4.x, x4.x, s);
        s = fmaf(w4.y, x4.y, s);
        s = fmaf(w4.z, x4.z, s);
        s = fmaf(w4.w, x4.w, s);
    }
    out[(size_t)b * NCLASS + tid] = s;
}

// ---------------- fallbacks (ws too small) ----------------------------------
__global__ __launch_bounds__(256)
void convert_flat_kernel(const float* __restrict__ emb, unsigned short* __restrict__ o)
{
    const int i = blockIdx.x * 256 + threadIdx.x;
    const float4 v = reinterpret_cast<const float4*>(emb)[i];
    ushort4 u;
    u.x = f2bf_rne(v.x); u.y = f2bf_rne(v.y);
    u.z = f2bf_rne(v.z); u.w = f2bf_rne(v.w);
    reinterpret_cast<ushort4*>(o)[i] = u;
}

__global__ __launch_bounds__(256, 4)
void pool_gemm_bf16_kernel(const int* __restrict__ diag_idx,
                           const int* __restrict__ proc_idx,
                           const unsigned short* __restrict__ embb,
                           const float* __restrict__ W,
                           const float* __restrict__ bias,
                           float* __restrict__ out)
{
    __shared__ float4 part4[4][64];
    __shared__ float  x_lds[TWO_D];

    const int b    = blockIdx.x;
    const int tid  = threadIdx.x;
    const int wave = tid >> 6;
    const int lane = tid & 63;

    const int half  = wave >> 1;
    const int chunk = wave & 1;
    const int* __restrict__ idx =
        (half == 0 ? diag_idx : proc_idx) + (size_t)b * NIDX + (size_t)chunk * (NIDX / 2);
    const int2* __restrict__ idx2 = reinterpret_cast<const int2*>(idx);

    const ushort4* __restrict__ emb4 = reinterpret_cast<const ushort4*>(embb);
    const int c = lane & 31;

    float4 acc = make_float4(0.f, 0.f, 0.f, 0.f);
    #pragma unroll 10
    for (int i = 0; i < NIDX / 4; ++i) {
        const int2 p = idx2[i];
        const int  r = (lane & 32) ? p.y : p.x;
        const ushort4 e = emb4[(size_t)r * (D / 4) + c];
        acc.x += uif((unsigned int)e.x << 16);
        acc.y += uif((unsigned int)e.y << 16);
        acc.z += uif((unsigned int)e.z << 16);
        acc.w += uif((unsigned int)e.w << 16);
    }
    part4[wave][lane] = acc;
    __syncthreads();

    {
        const int h   = tid >> 7;
        const int rem = tid & 127;
        const int cc  = rem >> 2;
        const int j   = rem & 3;
        const float* p0 = reinterpret_cast<const float*>(&part4[2 * h][cc]);
        const float* p1 = reinterpret_cast<const float*>(&part4[2 * h][cc + 32]);
        const float* p2 = reinterpret_cast<const float*>(&part4[2 * h + 1][cc]);
        const float* p3 = reinterpret_cast<const float*>(&part4[2 * h + 1][cc + 32]);
        x_lds[tid] = (p0[j] + p1[j] + p2[j] + p3[j]) * (1.0f / L);
    }
    __syncthreads();

    if (tid < NCLASS) {
        const float4* __restrict__ wrow =
            reinterpret_cast<const float4*>(W + (size_t)tid * TWO_D);
        const float4* __restrict__ xv = reinterpret_cast<const float4*>(x_lds);
        float s = bias[tid];
        #pragma unroll 8
        for (int k = 0; k < TWO_D / 4; ++k) {
            const float4 w4 = wrow[k];
            const float4 x4 = xv[k];
            s = fmaf(w4.x, x4.x, s);
            s = fmaf(w4.y, x4.y, s);
            s = fmaf(w4.z, x4.z, s);
            s = fmaf(w4.w, x4.w, s);
        }
        out[(size_t)b * NCLASS + tid] = s;
    }
}

__global__ __launch_bounds__(256, 4)
void pool_gemm_f32_kernel(const int* __restrict__ diag_idx,
                          const int* __restrict__ proc_idx,
                          const float* __restrict__ emb,
                          const float* __restrict__ W,
                          const float* __restrict__ bias,
                          float* __restrict__ out)
{
    __shared__ float4 part4[4][64];
    __shared__ float  x_lds[TWO_D];

    const int b    = blockIdx.x;
    const int tid  = threadIdx.x;
    const int wave = tid >> 6;
    const int lane = tid & 63;

    const int half  = wave >> 1;
    const int chunk = wave & 1;
    const int* __restrict__ idx =
        (half == 0 ? diag_idx : proc_idx) + (size_t)b * NIDX + (size_t)chunk * (NIDX / 2);
    const int2* __restrict__ idx2 = reinterpret_cast<const int2*>(idx);

    const float4* __restrict__ emb4 = reinterpret_cast<const float4*>(emb);
    const int c = lane & 31;

    float4 acc = make_float4(0.f, 0.f, 0.f, 0.f);
    #pragma unroll 5
    for (int i = 0; i < NIDX / 4; ++i) {
        const int2 p = idx2[i];
        const int  r = (lane & 32) ? p.y : p.x;
        const float4 e = emb4[(size_t)r * (D / 4) + c];
        acc.x += e.x; acc.y += e.y; acc.z += e.z; acc.w += e.w;
    }
    part4[wave][lane] = acc;
    __syncthreads();

    {
        const int h   = tid >> 7;
        const int rem = tid & 127;
        const int cc  = rem >> 2;
        const int j   = rem & 3;
        const float* p0 = reinterpret_cast<const float*>(&part4[2 * h][cc]);
        const float* p1 = reinterpret_cast<const float*>(&part4[2 * h][cc + 32]);
        const float* p2 = reinterpret_cast<const float*>(&part4[2 * h + 1][cc]);
        const float* p3 = reinterpret_cast<const float*>(&part4[2 * h + 1][cc + 32]);
        x_lds[tid] = (p0[j] + p1[j] + p2[j] + p3[j]) * (1.0f / L);
    }
    __syncthreads();

    if (tid < NCLASS) {
        const float4* __restrict__ wrow =
            reinterpret_cast<const float4*>(W + (size_t)tid * TWO_D);
        const float4* __restrict__ xv = reinterpret_cast<const float4*>(x_lds);
        float s = bias[tid];
        #pragma unroll 8
        for (int k = 0; k < TWO_D / 4; ++k) {
            const float4 w4 = wrow[k];
            const float4 x4 = xv[k];
            s = fmaf(w4.x, x4.x, s);
            s = fmaf(w4.y, x4.y, s);
            s = fmaf(w4.z, x4.z, s);
            s = fmaf(w4.w, x4.w, s);
        }
        out[(size_t)b * NCLASS + tid] = s;
    }
}

extern "C" void kernel_launch(void* const* d_in, const int* in_sizes, int n_in,
                              void* d_out, int out_size, void* d_ws, size_t ws_size,
                              hipStream_t stream)
{
    const int*   diag = (const int*)d_in[0];
    const int*   proc = (const int*)d_in[1];
    const float* emb  = (const float*)d_in[2];
    const float* W    = (const float*)d_in[3];
    const float* bias = (const float*)d_in[4];
    float*       out  = (float*)d_out;

    const size_t embb_bytes   = (size_t)NSLICE * SROWS_P * D * sizeof(unsigned short); // 25.602 MB
    const size_t sorted_bytes = (size_t)B * 2 * NIDX * sizeof(unsigned short);         // 8.192 MB
    const size_t offs_bytes   = (size_t)B * 2 * (NSLICE + 1) * sizeof(int);            // 147 KB
    const size_t pooled_bytes = (size_t)B * TWO_D * sizeof(float);                     // 2 MB
    const size_t need = embb_bytes + sorted_bytes + offs_bytes + pooled_bytes;

    const size_t emb_flat_bytes = (size_t)VOCAB * D * sizeof(unsigned short);          // 25.6 MB

    if (ws_size >= need) {
        char* p = (char*)d_ws;
        unsigned short* embb   = (unsigned short*)p;              p += embb_bytes;
        unsigned short* sorted = (unsigned short*)p;              p += sorted_bytes;
        int*            offs   = (int*)p;                         p += offs_bytes;
        float*          pooled = (float*)p;

        prep_kernel<<<12501 + B, 256, 0, stream>>>(emb, diag, proc,
                                                   embb, sorted, offs, pooled);
        slice_pool_kernel<<<B * NSLICE, 256, 0, stream>>>(embb, sorted, offs, pooled);
        head_kernel<<<B, 128, 0, stream>>>(pooled, W, bias, out);
    } else if (ws_size >= emb_flat_bytes) {
        unsigned short* embb = (unsigned short*)d_ws;
        convert_flat_kernel<<<(VOCAB * D / 4) / 256, 256, 0, stream>>>(emb, embb);
        pool_gemm_bf16_kernel<<<B, 256, 0, stream>>>(diag, proc, embb, W, bias, out);
    } else {
        pool_gemm_f32_kernel<<<B, 256, 0, stream>>>(diag, proc, emb, W, bias, out);
    }
}